// Round 16
// baseline (247.438 us; speedup 1.0000x reference)
//
#include <hip/hip_runtime.h>
#include <hip/hip_bf16.h>

#define M_DIM 8192
#define N_DIM 4096
#define K_DIM 4096

using bf16x8 = __attribute__((ext_vector_type(8))) short;
using f32x4  = __attribute__((ext_vector_type(4))) float;

// ---------- fp32 -> bf16 (RNE via bit math) ----------
__device__ __forceinline__ unsigned short f2bf(float f) {
    unsigned int u = __float_as_uint(f);
    unsigned int r = u + 0x7fffu + ((u >> 16) & 1u);
    return (unsigned short)(r >> 16);
}

// Single fused conversion: x (n4x float4s) then w (n4w float4s) into ws.
__global__ void cvt_both_f32_to_bf16(const float* __restrict__ x,
                                     const float* __restrict__ w,
                                     unsigned short* __restrict__ ws,
                                     int n4x, int n4w) {
    int i = blockIdx.x * blockDim.x + threadIdx.x;
    const int stride = gridDim.x * blockDim.x;
    const int total = n4x + n4w;
    uint2* dx = reinterpret_cast<uint2*>(ws);
    uint2* dw = reinterpret_cast<uint2*>(ws) + n4x;
    for (; i < total; i += stride) {
        const bool isX = i < n4x;
        const float4* s4 = isX ? reinterpret_cast<const float4*>(x)
                               : reinterpret_cast<const float4*>(w);
        const int j = isX ? i : i - n4x;
        float4 v = s4[j];
        uint2 o;
        o.x = (unsigned)f2bf(v.x) | ((unsigned)f2bf(v.y) << 16);
        o.y = (unsigned)f2bf(v.z) | ((unsigned)f2bf(v.w) << 16);
        (isX ? dx : dw)[j] = o;
    }
}

// ---------- async global->LDS, 16B per lane ----------
__device__ __forceinline__ void gload16(const unsigned short* g, char* l) {
    __builtin_amdgcn_global_load_lds(
        (const __attribute__((address_space(1))) void*)g,
        (__attribute__((address_space(3))) void*)l, 16, 0, 0);
}

// ============================================================================
// 256x256 bf16 MFMA GEMM — round 16: R15 with phases merged 4->2 per K-tile
// (halve barrier count). No setprio (R15 win). R14 epilogue.
//
// Per tile t (buf=t&1, XV=B0(t) regs, YV=B0(t+1) regs):
//  ph1: STAGE A1(t+1)->nbuf, A0(t+2)->buf ; read bv1<-B1(t)-buf ;
//       MFMA q00 (av=A0,XV), q01 (av=A0,bv1) ; overlay av<-A1(t)-buf ;
//       vmcnt(4) barrier
//  ph2: STAGE B0(t+2)->buf, B1(t+2)->buf ; read YV<-B0(t+1)-nbuf ;
//       MFMA q11 (av=A1,bv1), q10 (av=A1,XV) ; overlay av<-A0(t+1)-nbuf ;
//       vmcnt(4) barrier
//
// Slot-death audit (stage vs last cross-wave read, >=1 barrier apart):
//   A0-buf: read ph2(t-1) [LOAD_A(0,nb), nb(t-1)=buf(t)] ✓
//   A1-nbuf: read ph1(t-1) [LOAD_A(1,buf), buf(t-1)=nbuf(t)] ✓
//   B0-buf: read ph2(t-1) [LOAD_B(0,nb,YV)] ✓
//   B1-buf: read ph1(t)   [LOAD_B(1,buf,bv1)] — ph1-end barrier separates ✓
// vmcnt(4) coverage (4 loads staged per phase):
//   W1(t): outstanding = ph2(t-1)4 + ph1(t)4 = 8 -> drains ph2(t-1)'s
//          {B0(t+1),B1(t+1)} before ph2(t)/ph1(t+1) read them ✓
//   W2(t): drains ph1(t)'s {A1(t+1),A0(t+2)} before ph1(t+1) reads A1(t+1) ✓
// Prologue: stage A0(0),B0(0),B1(0),A1(0),A0(1),B0(1),B1(1); vmcnt(4) leaves
// {B0(1),B1(1)} outstanding = steady-state entry; pre-read av<-A0(0),
// bvX<-B0(0). Tail stages wrap (dummy -> dead slots); vmcnt(0) after loop.
// MFMA feeding: all quadrants cross-barrier-fed except q01's bv1 (same-phase,
// covered by q00's 16-MFMA shadow).
// ============================================================================
__global__ __launch_bounds__(512, 2) void gemm_bf16_256_8ph(
        const unsigned short* __restrict__ xb,   // [M,K] bf16 bits
        const unsigned short* __restrict__ wb,   // [N,K] bf16 bits
        const float* __restrict__ bias,          // [N]
        float* __restrict__ out) {               // [M,N]
    extern __shared__ char lds[];
    char* ldsA = lds;           // [2 buf][2 q][16384 B]
    char* ldsB = lds + 65536;   // [2 buf][2 p][16384 B]

    // L2-aware XCD chunk map (round 4: FETCH 549->201 MB)
    const int bid = blockIdx.x;
    const int xcd = bid & 7;
    const int c   = bid >> 3;                 // 0..63
    const int tm  = (xcd >> 1) * 8 + (c & 7); // 0..31
    const int tn  = (xcd & 1) * 8 + (c >> 3); // 0..15
    const int r0 = tm * 256;
    const int c0 = tn * 256;

    const int tid  = threadIdx.x;
    const int lane = tid & 63;
    const int wave = tid >> 6;        // 0..7
    const int wm = wave >> 2;         // 0..1  (128-row half)
    const int wn = wave & 3;          // 0..3  (64-col strip)
    const int lr = lane & 15;
    const int t4 = lane >> 4;

    // --- ds_read offsets (bytes within one 16KB region), T2-swizzled ---
    int aRd[4][2], bRd[2][2];
    const int swz = (lr & 7) << 4;
#pragma unroll
    for (int ks = 0; ks < 2; ++ks) {
        const int cb = (ks * 64 + t4 * 16) ^ swz;
#pragma unroll
        for (int m = 0; m < 4; ++m)
            aRd[m][ks] = (wm * 64 + m * 16 + lr) * 128 + cb;
#pragma unroll
        for (int n = 0; n < 2; ++n)
            bRd[n][ks] = (wn * 32 + n * 16 + lr) * 128 + cb;
    }

    // --- staging: wave-uniform LDS dest (HW adds lane*16), inverse-swizzled
    //     global source ---
    const int rowInBlk = lane >> 3;                       // 0..7
    const int sChunk   = ((lane & 7) ^ rowInBlk) * 8;     // element offset
    int aSrcB[2], bSrcB[2], dstOff[2];
#pragma unroll
    for (int l = 0; l < 2; ++l) {
        const int R0 = wave * 16 + l * 8;                 // lds row base 0..120
        aSrcB[l] = (r0 + (R0 >> 6) * 128 + (R0 & 63) + rowInBlk) * K_DIM + sChunk;
        bSrcB[l] = (c0 + (R0 >> 5) * 64  + (R0 & 31) + rowInBlk) * K_DIM + sChunk;
        dstOff[l] = R0 * 128;                             // wave-uniform
    }

    auto STAGE_A = [&](int q, int kt, int nb) {
#pragma unroll
        for (int l = 0; l < 2; ++l)
            gload16(xb + aSrcB[l] + q * 64 * K_DIM + kt * 64,
                    ldsA + nb * 32768 + q * 16384 + dstOff[l]);
    };
    auto STAGE_B = [&](int p, int kt, int nb) {
#pragma unroll
        for (int l = 0; l < 2; ++l)
            gload16(wb + bSrcB[l] + p * 32 * K_DIM + kt * 64,
                    ldsB + nb * 32768 + p * 16384 + dstOff[l]);
    };

    f32x4 acc[8][4];
#pragma unroll
    for (int i = 0; i < 8; ++i)
#pragma unroll
        for (int j = 0; j < 4; ++j)
            acc[i][j] = (f32x4){0.f, 0.f, 0.f, 0.f};

    bf16x8 av[4][2], bvA[2][2], bvB[2][2], bv1[2][2];

// No setprio (R15 ablation: lockstep structure, m190-mode).
#define MFMA_QUAD(M0, N0, BV)                                                  \
    do {                                                                       \
        _Pragma("unroll") for (int m = 0; m < 4; ++m)                          \
        _Pragma("unroll") for (int n = 0; n < 2; ++n)                          \
        _Pragma("unroll") for (int ks = 0; ks < 2; ++ks)                       \
            acc[(M0) + m][(N0) + n] = __builtin_amdgcn_mfma_f32_16x16x32_bf16( \
                av[m][ks], BV[n][ks], acc[(M0) + m][(N0) + n], 0, 0, 0);       \
    } while (0)

#define LOAD_A(Q, BUF)                                                         \
    _Pragma("unroll") for (int m = 0; m < 4; ++m)                              \
    _Pragma("unroll") for (int ks = 0; ks < 2; ++ks)                           \
        av[m][ks] = *(const bf16x8*)(ldsA + (BUF) * 32768 + (Q) * 16384 + aRd[m][ks]);

#define LOAD_B(P, BUF, BV)                                                     \
    _Pragma("unroll") for (int n = 0; n < 2; ++n)                              \
    _Pragma("unroll") for (int ks = 0; ks < 2; ++ks)                           \
        BV[n][ks] = *(const bf16x8*)(ldsB + (BUF) * 32768 + (P) * 16384 + bRd[n][ks]);

    const int NT = K_DIM / 64;   // 64

#define TILE_BODY(T, BUF, XV, YV)                                              \
    do {                                                                       \
        const int nb_  = (BUF) ^ 1;                                           \
        const int kt1_ = ((T) + 1) & (NT - 1);                                 \
        const int kt2_ = ((T) + 2) & (NT - 1);                                 \
        /* ph1: stages A; reads bv1, then overlay av<-A1(t) after q00/q01 */   \
        STAGE_A(1, kt1_, nb_);                                                 \
        STAGE_A(0, kt2_, (BUF));                                               \
        LOAD_B(1, (BUF), bv1);                                                 \
        MFMA_QUAD(0, 0, XV);                                                   \
        MFMA_QUAD(0, 2, bv1);                                                  \
        LOAD_A(1, (BUF));                                                      \
        asm volatile("s_waitcnt vmcnt(4)\n\ts_barrier" ::: "memory");          \
        /* ph2: stages B; reads YV, then overlay av<-A0(t+1) after q11/q10 */  \
        STAGE_B(0, kt2_, (BUF));                                               \
        STAGE_B(1, kt2_, (BUF));                                               \
        LOAD_B(0, nb_, YV);                                                    \
        MFMA_QUAD(4, 2, bv1);                                                  \
        MFMA_QUAD(4, 0, XV);                                                   \
        LOAD_A(0, nb_);                                                        \
        asm volatile("s_waitcnt vmcnt(4)\n\ts_barrier" ::: "memory");          \
    } while (0)

    // --- prologue: t0 {A0,B0,B1,A1} + t1 {A0,B0,B1}; vmcnt(4) leaves
    //     {B0(1),B1(1)} in flight = steady-state entry ---
    STAGE_A(0, 0, 0);
    STAGE_B(0, 0, 0);
    STAGE_B(1, 0, 0);
    STAGE_A(1, 0, 0);
    STAGE_A(0, 1, 1);
    STAGE_B(0, 1, 1);
    STAGE_B(1, 1, 1);
    asm volatile("s_waitcnt vmcnt(4)\n\ts_barrier" ::: "memory");
    LOAD_A(0, 0);          // av  <- A0(0)
    LOAD_B(0, 0, bvA);     // bvA <- B0(0)

    for (int tt = 0; tt < NT / 2; ++tt) {
        TILE_BODY(2 * tt,     0, bvA, bvB);
        TILE_BODY(2 * tt + 1, 1, bvB, bvA);
    }
    // full drain before LDS reuse (in-flight dummy stages + dead ds_reads)
    asm volatile("s_waitcnt vmcnt(0) lgkmcnt(0)" ::: "memory");
    __syncthreads();

    // --- epilogue (R14): LDS transpose -> 1KB-segment nontemporal stores ---
    float* ldsF = (float*)lds;               // [64][260] f32 = 66.6 KB
    const int FS = 260;                      // pad: 2-way write aliasing = free
    float bvs[4];
#pragma unroll
    for (int ni = 0; ni < 4; ++ni)
        bvs[ni] = bias[c0 + wn * 64 + (ni >> 1) * 32 + (ni & 1) * 16 + lr];

#pragma unroll
    for (int Q = 0; Q < 4; ++Q) {
        if (wm == (Q >> 1)) {
#pragma unroll
            for (int miL = 0; miL < 4; ++miL) {
                const int mi = (Q & 1) * 4 + miL;
#pragma unroll
                for (int ni = 0; ni < 4; ++ni) {
                    const int col  = wn * 64 + (ni >> 1) * 32 + (ni & 1) * 16 + lr;
                    const int lrow = miL * 16 + t4 * 4;
#pragma unroll
                    for (int j = 0; j < 4; ++j)
                        ldsF[(lrow + j) * FS + col] = acc[mi][ni][j] + bvs[ni];
                }
            }
        }
        __syncthreads();
        const int rowQ = r0 + (Q >> 1) * 128 + (Q & 1) * 64;
#pragma unroll
        for (int it = 0; it < 8; ++it) {
            const int lrow = wave + 8 * it;          // 0..63
            const f32x4 v = *(const f32x4*)&ldsF[lrow * FS + lane * 4];
            __builtin_nontemporal_store(
                v, (f32x4*)&out[(size_t)(rowQ + lrow) * N_DIM + c0 + lane * 4]);
        }
        __syncthreads();
    }
#undef TILE_BODY
#undef MFMA_QUAD
#undef LOAD_A
#undef LOAD_B
}

// ============================================================================
// Proven round-1 128x128 kernel — runtime fallback if dynamic LDS
// cannot be enabled.
// ============================================================================
__global__ __launch_bounds__(256) void gemm_bf16_mfma(
        const unsigned short* __restrict__ xb,
        const unsigned short* __restrict__ wb,
        const float* __restrict__ bias,
        float* __restrict__ out) {
    __shared__ unsigned short sA[128 * 64];
    __shared__ unsigned short sB[128 * 64];

    const int nwg = (M_DIM / 128) * (N_DIM / 128);
    const int q = nwg / 8;
    int bid = blockIdx.x;
    int bid2 = (bid & 7) * q + (bid >> 3);
    const int tm = bid2 & 63;
    const int tn = bid2 >> 6;
    const int r0 = tm * 128;
    const int c0 = tn * 128;

    const int tid  = threadIdx.x;
    const int lane = tid & 63;
    const int wave = tid >> 6;
    const int wr = wave >> 1;
    const int wc = wave & 1;
    const int lr = lane & 15;
    const int t  = lane >> 4;

    int aoff[2][4], boff[2][4];
#pragma unroll
    for (int m = 0; m < 4; ++m) {
        int rowA = wr * 64 + m * 16 + lr;
        int swA  = (rowA & 7) << 4;
        int rowB = wc * 64 + m * 16 + lr;
        int swB  = (rowB & 7) << 4;
#pragma unroll
        for (int kk = 0; kk < 2; ++kk) {
            int cb = kk * 64 + t * 16;
            aoff[kk][m] = rowA * 64 + ((cb ^ swA) >> 1);
            boff[kk][m] = rowB * 64 + ((cb ^ swB) >> 1);
        }
    }

    const int sRow   = lane >> 3;
    const int sChunk = (lane & 7) ^ sRow;
    int aSrc[4], bSrc[4];
    char* ldsA[4];
    char* ldsB[4];
#pragma unroll
    for (int r = 0; r < 4; ++r) {
        int row = r * 32 + wave * 8 + sRow;
        aSrc[r] = (r0 + row) * K_DIM + sChunk * 8;
        bSrc[r] = (c0 + row) * K_DIM + sChunk * 8;
        ldsA[r] = (char*)sA + (r * 4 + wave) * 1024;
        ldsB[r] = (char*)sB + (r * 4 + wave) * 1024;
    }

    f32x4 acc[4][4];
#pragma unroll
    for (int m = 0; m < 4; ++m)
#pragma unroll
        for (int n = 0; n < 4; ++n)
            acc[m][n] = (f32x4){0.f, 0.f, 0.f, 0.f};

    for (int kt = 0; kt < K_DIM / 64; ++kt) {
        const int ko = kt * 64;
#pragma unroll
        for (int r = 0; r < 4; ++r) {
            gload16(xb + aSrc[r] + ko, ldsA[r]);
            gload16(wb + bSrc[r] + ko, ldsB[r]);
        }
        __syncthreads();
#pragma unroll
        for (int kk = 0; kk < 2; ++kk) {
            bf16x8 av[4], bv[4];
#pragma unroll
            for (int m = 0; m < 4; ++m)
                av[m] = *reinterpret_cast<const bf16x8*>(sA + aoff[kk][m]);
#pragma unroll
            for (int n = 0; n < 4; ++n)
                bv[n] = *reinterpret_cast<const bf16x8*>(sB + boff[kk][n]);
#pragma unroll
            for (int m = 0; m < 4; ++m)
#pragma unroll
                for (int n = 0; n < 4; ++n)
                    acc[m][n] = __builtin_amdgcn_mfma_f32_16x16x32_bf16(
                        av[m], bv[n], acc[m][n], 0, 0, 0);
        }
        __syncthreads();
    }

#pragma unroll
    for (int n = 0; n < 4; ++n) {
        const int col = c0 + wc * 64 + n * 16 + lr;
        const float bv = bias[col];
#pragma unroll
        for (int m = 0; m < 4; ++m) {
            const int row0 = r0 + wr * 64 + m * 16 + t * 4;
#pragma unroll
            for (int j = 0; j < 4; ++j)
                out[(row0 + j) * N_DIM + col] = acc[m][n][j] + bv;
        }
    }
}

// ---------- fp32 fallback (only if ws too small) ----------
__global__ void fallback_gemm_f32(const float* __restrict__ x,
                                  const float* __restrict__ w,
                                  const float* __restrict__ bias,
                                  float* __restrict__ out) {
    __shared__ float sX[2][4096];
    const int tid = threadIdx.x;
    const int col = blockIdx.x * 256 + tid;
    const int row0 = blockIdx.y * 2;
    for (int i = tid * 4; i < 8192; i += 1024) {
        int r = i >> 12, c = i & 4095;
        *(float4*)&sX[r][c] = *(const float4*)&x[(size_t)(row0 + r) * 4096 + c];
    }
    __syncthreads();
    const float4* wrow = (const float4*)&w[(size_t)col * 4096];
    float a0 = 0.f, a1 = 0.f;
    for (int k4 = 0; k4 < 1024; ++k4) {
        float4 wv = wrow[k4];
        int k = k4 << 2;
        a0 += wv.x * sX[0][k] + wv.y * sX[0][k + 1] + wv.z * sX[0][k + 2] + wv.w * sX[0][k + 3];
        a1 += wv.x * sX[1][k] + wv.y * sX[1][k + 1] + wv.z * sX[1][k + 2] + wv.w * sX[1][k + 3];
    }
    float bv = bias[col];
    out[(size_t)row0 * 4096 + col] = a0 + bv;
    out[(size_t)(row0 + 1) * 4096 + col] = a1 + bv;
}

extern "C" void kernel_launch(void* const* d_in, const int* in_sizes, int n_in,
                              void* d_out, int out_size, void* d_ws, size_t ws_size,
                              hipStream_t stream) {
    const float* x    = (const float*)d_in[0];
    const float* w    = (const float*)d_in[1];
    const float* bias = (const float*)d_in[2];
    float* out = (float*)d_out;

    const size_t nX = (size_t)M_DIM * K_DIM;
    const size_t nW = (size_t)N_DIM * K_DIM;
    const size_t need = (nX + nW) * sizeof(unsigned short);

    if (ws_size >= need) {
        unsigned short* xb = (unsigned short*)d_ws;
        unsigned short* wb = xb + nX;
        cvt_both_f32_to_bf16<<<3072, 256, 0, stream>>>(
            x, w, (unsigned short*)d_ws, (int)(nX / 4), (int)(nW / 4));
        hipError_t e = hipFuncSetAttribute(
            (const void*)gemm_bf16_256_8ph,
            hipFuncAttributeMaxDynamicSharedMemorySize, 131072);
        if (e == hipSuccess) {
            gemm_bf16_256_8ph<<<(M_DIM / 256) * (N_DIM / 256), 512, 131072, stream>>>(
                xb, wb, bias, out);
        } else {
            gemm_bf16_mfma<<<(M_DIM / 128) * (N_DIM / 128), 256, 0, stream>>>(
                xb, wb, bias, out);
        }
    } else {
        fallback_gemm_f32<<<dim3(N_DIM / 256, M_DIM / 2), 256, 0, stream>>>(x, w, bias, out);
    }
}

// Round 17
// 244.883 us; speedup vs baseline: 1.0104x; 1.0104x over previous
//
#include <hip/hip_runtime.h>
#include <hip/hip_bf16.h>

#define M_DIM 8192
#define N_DIM 4096
#define K_DIM 4096

using bf16x8 = __attribute__((ext_vector_type(8))) short;
using f32x4  = __attribute__((ext_vector_type(4))) float;

// ---------- fp32 -> bf16 (RNE via bit math) ----------
__device__ __forceinline__ unsigned short f2bf(float f) {
    unsigned int u = __float_as_uint(f);
    unsigned int r = u + 0x7fffu + ((u >> 16) & 1u);
    return (unsigned short)(r >> 16);
}

// Single fused conversion: x (n4x float4s) then w (n4w float4s) into ws.
__global__ void cvt_both_f32_to_bf16(const float* __restrict__ x,
                                     const float* __restrict__ w,
                                     unsigned short* __restrict__ ws,
                                     int n4x, int n4w) {
    int i = blockIdx.x * blockDim.x + threadIdx.x;
    const int stride = gridDim.x * blockDim.x;
    const int total = n4x + n4w;
    uint2* dx = reinterpret_cast<uint2*>(ws);
    uint2* dw = reinterpret_cast<uint2*>(ws) + n4x;
    for (; i < total; i += stride) {
        const bool isX = i < n4x;
        const float4* s4 = isX ? reinterpret_cast<const float4*>(x)
                               : reinterpret_cast<const float4*>(w);
        const int j = isX ? i : i - n4x;
        float4 v = s4[j];
        uint2 o;
        o.x = (unsigned)f2bf(v.x) | ((unsigned)f2bf(v.y) << 16);
        o.y = (unsigned)f2bf(v.z) | ((unsigned)f2bf(v.w) << 16);
        (isX ? dx : dw)[j] = o;
    }
}

// ---------- async global->LDS, 16B per lane ----------
__device__ __forceinline__ void gload16(const unsigned short* g, char* l) {
    __builtin_amdgcn_global_load_lds(
        (const __attribute__((address_space(1))) void*)g,
        (__attribute__((address_space(3))) void*)l, 16, 0, 0);
}

// ============================================================================
// 256x256 bf16 MFMA GEMM — round 17 = round 15 verbatim (measured session
// best: 245.3 us total, GEMM 217.5 us, MfmaUtil 57.5%, conflicts 0).
//
// Structure: R6 cross-barrier K-loop (2-tile prefetch, vmcnt(6) ledger),
// NO setprio (R15 ablation: lockstep structure, m190-mode, -11 us),
// R14 epilogue (LDS-transposed 1KB-segment nontemporal stores, -35 MB
// write over-traffic), R4 L2-aware XCD chunk map (FETCH 549->201 MB),
// T2 swizzle (bank conflicts 0).
//
// K-loop per tile t (buf=t&1, X=B0(t) regs, Y=B0(t+1) regs):
//  I1: stage A1(t+1)->nbuf ; read bv1<-B1(t)      ; MFMA q00 (av=A0, X); bar
//  I2: stage A0(t+2)->buf  ; MFMA q01 (av=A0,bv1) ; read av<-A1(t); vmcnt(6) bar
//  I3: stage B0(t+2)->buf  ; read Y<-B0(t+1)      ; MFMA q11 (av=A1,bv1); bar
//  I4: stage B1(t+2)->buf  ; MFMA q10 (av=A1, X)  ; read av<-A0(t+1); vmcnt(6) bar
// (ledger + slot-death audit in round-6 notes; refcheck'd rounds 6,8,12,14,15.)
// ============================================================================
__global__ __launch_bounds__(512, 2) void gemm_bf16_256_8ph(
        const unsigned short* __restrict__ xb,   // [M,K] bf16 bits
        const unsigned short* __restrict__ wb,   // [N,K] bf16 bits
        const float* __restrict__ bias,          // [N]
        float* __restrict__ out) {               // [M,N]
    extern __shared__ char lds[];
    char* ldsA = lds;           // [2 buf][2 q][16384 B]
    char* ldsB = lds + 65536;   // [2 buf][2 p][16384 B]

    // L2-aware XCD chunk map (round 4: FETCH 549->201 MB)
    const int bid = blockIdx.x;
    const int xcd = bid & 7;
    const int c   = bid >> 3;                 // 0..63
    const int tm  = (xcd >> 1) * 8 + (c & 7); // 0..31
    const int tn  = (xcd & 1) * 8 + (c >> 3); // 0..15
    const int r0 = tm * 256;
    const int c0 = tn * 256;

    const int tid  = threadIdx.x;
    const int lane = tid & 63;
    const int wave = tid >> 6;        // 0..7
    const int wm = wave >> 2;         // 0..1  (128-row half)
    const int wn = wave & 3;          // 0..3  (64-col strip)
    const int lr = lane & 15;
    const int t4 = lane >> 4;

    // --- ds_read offsets (bytes within one 16KB region), T2-swizzled ---
    int aRd[4][2], bRd[2][2];
    const int swz = (lr & 7) << 4;
#pragma unroll
    for (int ks = 0; ks < 2; ++ks) {
        const int cb = (ks * 64 + t4 * 16) ^ swz;
#pragma unroll
        for (int m = 0; m < 4; ++m)
            aRd[m][ks] = (wm * 64 + m * 16 + lr) * 128 + cb;
#pragma unroll
        for (int n = 0; n < 2; ++n)
            bRd[n][ks] = (wn * 32 + n * 16 + lr) * 128 + cb;
    }

    // --- staging: wave-uniform LDS dest (HW adds lane*16), inverse-swizzled
    //     global source ---
    const int rowInBlk = lane >> 3;                       // 0..7
    const int sChunk   = ((lane & 7) ^ rowInBlk) * 8;     // element offset
    int aSrcB[2], bSrcB[2], dstOff[2];
#pragma unroll
    for (int l = 0; l < 2; ++l) {
        const int R0 = wave * 16 + l * 8;                 // lds row base 0..120
        aSrcB[l] = (r0 + (R0 >> 6) * 128 + (R0 & 63) + rowInBlk) * K_DIM + sChunk;
        bSrcB[l] = (c0 + (R0 >> 5) * 64  + (R0 & 31) + rowInBlk) * K_DIM + sChunk;
        dstOff[l] = R0 * 128;                             // wave-uniform
    }

    auto STAGE_A = [&](int q, int kt, int nb) {
#pragma unroll
        for (int l = 0; l < 2; ++l)
            gload16(xb + aSrcB[l] + q * 64 * K_DIM + kt * 64,
                    ldsA + nb * 32768 + q * 16384 + dstOff[l]);
    };
    auto STAGE_B = [&](int p, int kt, int nb) {
#pragma unroll
        for (int l = 0; l < 2; ++l)
            gload16(wb + bSrcB[l] + p * 32 * K_DIM + kt * 64,
                    ldsB + nb * 32768 + p * 16384 + dstOff[l]);
    };

    f32x4 acc[8][4];
#pragma unroll
    for (int i = 0; i < 8; ++i)
#pragma unroll
        for (int j = 0; j < 4; ++j)
            acc[i][j] = (f32x4){0.f, 0.f, 0.f, 0.f};

    bf16x8 av[4][2], bvA[2][2], bvB[2][2], bv1[2][2];

// No setprio (R15 ablation: lockstep structure, m190-mode).
#define MFMA_QUAD(M0, N0, BV)                                                  \
    do {                                                                       \
        _Pragma("unroll") for (int m = 0; m < 4; ++m)                          \
        _Pragma("unroll") for (int n = 0; n < 2; ++n)                          \
        _Pragma("unroll") for (int ks = 0; ks < 2; ++ks)                       \
            acc[(M0) + m][(N0) + n] = __builtin_amdgcn_mfma_f32_16x16x32_bf16( \
                av[m][ks], BV[n][ks], acc[(M0) + m][(N0) + n], 0, 0, 0);       \
    } while (0)

#define LOAD_A(Q, BUF)                                                         \
    _Pragma("unroll") for (int m = 0; m < 4; ++m)                              \
    _Pragma("unroll") for (int ks = 0; ks < 2; ++ks)                           \
        av[m][ks] = *(const bf16x8*)(ldsA + (BUF) * 32768 + (Q) * 16384 + aRd[m][ks]);

#define LOAD_B(P, BUF, BV)                                                     \
    _Pragma("unroll") for (int n = 0; n < 2; ++n)                              \
    _Pragma("unroll") for (int ks = 0; ks < 2; ++ks)                           \
        BV[n][ks] = *(const bf16x8*)(ldsB + (BUF) * 32768 + (P) * 16384 + bRd[n][ks]);

    const int NT = K_DIM / 64;   // 64

#define TILE_BODY(T, BUF, XV, YV)                                              \
    do {                                                                       \
        const int nb_  = (BUF) ^ 1;                                           \
        const int kt1_ = ((T) + 1) & (NT - 1);                                 \
        const int kt2_ = ((T) + 2) & (NT - 1);                                 \
        /* I1: MFMA q00 (av=A0, X); read B1(t) */                              \
        STAGE_A(1, kt1_, nb_);                                                 \
        LOAD_B(1, (BUF), bv1);                                                 \
        MFMA_QUAD(0, 0, XV);                                                   \
        asm volatile("s_barrier" ::: "memory");                                \
        /* I2: MFMA q01 (av=A0, bv1); then overlay-read av<-A1(t) */           \
        STAGE_A(0, kt2_, (BUF));                                               \
        MFMA_QUAD(0, 2, bv1);                                                  \
        LOAD_A(1, (BUF));                                                      \
        asm volatile("s_waitcnt vmcnt(6)\n\ts_barrier" ::: "memory");          \
        /* I3: MFMA q11 (av=A1, bv1); read Y<-B0(t+1) */                       \
        STAGE_B(0, kt2_, (BUF));                                               \
        LOAD_B(0, nb_, YV);                                                    \
        MFMA_QUAD(4, 2, bv1);                                                  \
        asm volatile("s_barrier" ::: "memory");                                \
        /* I4: MFMA q10 (av=A1, X); then overlay-read av<-A0(t+1) */           \
        STAGE_B(1, kt2_, (BUF));                                               \
        MFMA_QUAD(4, 0, XV);                                                   \
        LOAD_A(0, nb_);                                                        \
        asm volatile("s_waitcnt vmcnt(6)\n\ts_barrier" ::: "memory");          \
    } while (0)

    // --- prologue: t0 full + t1 {A0,B0,B1}; land t0; pre-read A0(0), B0(0) ---
    STAGE_A(0, 0, 0);
    STAGE_B(0, 0, 0);
    STAGE_B(1, 0, 0);
    STAGE_A(1, 0, 0);
    STAGE_A(0, 1, 1);
    STAGE_B(0, 1, 1);
    STAGE_B(1, 1, 1);
    asm volatile("s_waitcnt vmcnt(6)\n\ts_barrier" ::: "memory");
    LOAD_A(0, 0);          // av  <- A0(0)
    LOAD_B(0, 0, bvA);     // bvA <- B0(0)

    for (int tt = 0; tt < NT / 2; ++tt) {
        TILE_BODY(2 * tt,     0, bvA, bvB);
        TILE_BODY(2 * tt + 1, 1, bvB, bvA);
    }
    // full drain before LDS reuse (in-flight dummy stages + dead ds_reads)
    asm volatile("s_waitcnt vmcnt(0) lgkmcnt(0)" ::: "memory");
    __syncthreads();

    // --- epilogue (R14): LDS transpose -> 1KB-segment nontemporal stores ---
    float* ldsF = (float*)lds;               // [64][260] f32 = 66.6 KB
    const int FS = 260;                      // pad: 2-way write aliasing = free
    float bvs[4];
#pragma unroll
    for (int ni = 0; ni < 4; ++ni)
        bvs[ni] = bias[c0 + wn * 64 + (ni >> 1) * 32 + (ni & 1) * 16 + lr];

#pragma unroll
    for (int Q = 0; Q < 4; ++Q) {
        if (wm == (Q >> 1)) {
#pragma unroll
            for (int miL = 0; miL < 4; ++miL) {
                const int mi = (Q & 1) * 4 + miL;
#pragma unroll
                for (int ni = 0; ni < 4; ++ni) {
                    const int col  = wn * 64 + (ni >> 1) * 32 + (ni & 1) * 16 + lr;
                    const int lrow = miL * 16 + t4 * 4;
#pragma unroll
                    for (int j = 0; j < 4; ++j)
                        ldsF[(lrow + j) * FS + col] = acc[mi][ni][j] + bvs[ni];
                }
            }
        }
        __syncthreads();
        const int rowQ = r0 + (Q >> 1) * 128 + (Q & 1) * 64;
#pragma unroll
        for (int it = 0; it < 8; ++it) {
            const int lrow = wave + 8 * it;          // 0..63
            const f32x4 v = *(const f32x4*)&ldsF[lrow * FS + lane * 4];
            __builtin_nontemporal_store(
                v, (f32x4*)&out[(size_t)(rowQ + lrow) * N_DIM + c0 + lane * 4]);
        }
        __syncthreads();
    }
#undef TILE_BODY
#undef MFMA_QUAD
#undef LOAD_A
#undef LOAD_B
}

// ============================================================================
// Proven round-1 128x128 kernel — runtime fallback if dynamic LDS
// cannot be enabled.
// ============================================================================
__global__ __launch_bounds__(256) void gemm_bf16_mfma(
        const unsigned short* __restrict__ xb,
        const unsigned short* __restrict__ wb,
        const float* __restrict__ bias,
        float* __restrict__ out) {
    __shared__ unsigned short sA[128 * 64];
    __shared__ unsigned short sB[128 * 64];

    const int nwg = (M_DIM / 128) * (N_DIM / 128);
    const int q = nwg / 8;
    int bid = blockIdx.x;
    int bid2 = (bid & 7) * q + (bid >> 3);
    const int tm = bid2 & 63;
    const int tn = bid2 >> 6;
    const int r0 = tm * 128;
    const int c0 = tn * 128;

    const int tid  = threadIdx.x;
    const int lane = tid & 63;
    const int wave = tid >> 6;
    const int wr = wave >> 1;
    const int wc = wave & 1;
    const int lr = lane & 15;
    const int t  = lane >> 4;

    int aoff[2][4], boff[2][4];
#pragma unroll
    for (int m = 0; m < 4; ++m) {
        int rowA = wr * 64 + m * 16 + lr;
        int swA  = (rowA & 7) << 4;
        int rowB = wc * 64 + m * 16 + lr;
        int swB  = (rowB & 7) << 4;
#pragma unroll
        for (int kk = 0; kk < 2; ++kk) {
            int cb = kk * 64 + t * 16;
            aoff[kk][m] = rowA * 64 + ((cb ^ swA) >> 1);
            boff[kk][m] = rowB * 64 + ((cb ^ swB) >> 1);
        }
    }

    const int sRow   = lane >> 3;
    const int sChunk = (lane & 7) ^ sRow;
    int aSrc[4], bSrc[4];
    char* ldsA[4];
    char* ldsB[4];
#pragma unroll
    for (int r = 0; r < 4; ++r) {
        int row = r * 32 + wave * 8 + sRow;
        aSrc[r] = (r0 + row) * K_DIM + sChunk * 8;
        bSrc[r] = (c0 + row) * K_DIM + sChunk * 8;
        ldsA[r] = (char*)sA + (r * 4 + wave) * 1024;
        ldsB[r] = (char*)sB + (r * 4 + wave) * 1024;
    }

    f32x4 acc[4][4];
#pragma unroll
    for (int m = 0; m < 4; ++m)
#pragma unroll
        for (int n = 0; n < 4; ++n)
            acc[m][n] = (f32x4){0.f, 0.f, 0.f, 0.f};

    for (int kt = 0; kt < K_DIM / 64; ++kt) {
        const int ko = kt * 64;
#pragma unroll
        for (int r = 0; r < 4; ++r) {
            gload16(xb + aSrc[r] + ko, ldsA[r]);
            gload16(wb + bSrc[r] + ko, ldsB[r]);
        }
        __syncthreads();
#pragma unroll
        for (int kk = 0; kk < 2; ++kk) {
            bf16x8 av[4], bv[4];
#pragma unroll
            for (int m = 0; m < 4; ++m)
                av[m] = *reinterpret_cast<const bf16x8*>(sA + aoff[kk][m]);
#pragma unroll
            for (int n = 0; n < 4; ++n)
                bv[n] = *reinterpret_cast<const bf16x8*>(sB + boff[kk][n]);
#pragma unroll
            for (int m = 0; m < 4; ++m)
#pragma unroll
                for (int n = 0; n < 4; ++n)
                    acc[m][n] = __builtin_amdgcn_mfma_f32_16x16x32_bf16(
                        av[m], bv[n], acc[m][n], 0, 0, 0);
        }
        __syncthreads();
    }

#pragma unroll
    for (int n = 0; n < 4; ++n) {
        const int col = c0 + wc * 64 + n * 16 + lr;
        const float bv = bias[col];
#pragma unroll
        for (int m = 0; m < 4; ++m) {
            const int row0 = r0 + wr * 64 + m * 16 + t * 4;
#pragma unroll
            for (int j = 0; j < 4; ++j)
                out[(row0 + j) * N_DIM + col] = acc[m][n][j] + bv;
        }
    }
}

// ---------- fp32 fallback (only if ws too small) ----------
__global__ void fallback_gemm_f32(const float* __restrict__ x,
                                  const float* __restrict__ w,
                                  const float* __restrict__ bias,
                                  float* __restrict__ out) {
    __shared__ float sX[2][4096];
    const int tid = threadIdx.x;
    const int col = blockIdx.x * 256 + tid;
    const int row0 = blockIdx.y * 2;
    for (int i = tid * 4; i < 8192; i += 1024) {
        int r = i >> 12, c = i & 4095;
        *(float4*)&sX[r][c] = *(const float4*)&x[(size_t)(row0 + r) * 4096 + c];
    }
    __syncthreads();
    const float4* wrow = (const float4*)&w[(size_t)col * 4096];
    float a0 = 0.f, a1 = 0.f;
    for (int k4 = 0; k4 < 1024; ++k4) {
        float4 wv = wrow[k4];
        int k = k4 << 2;
        a0 += wv.x * sX[0][k] + wv.y * sX[0][k + 1] + wv.z * sX[0][k + 2] + wv.w * sX[0][k + 3];
        a1 += wv.x * sX[1][k] + wv.y * sX[1][k + 1] + wv.z * sX[1][k + 2] + wv.w * sX[1][k + 3];
    }
    float bv = bias[col];
    out[(size_t)row0 * 4096 + col] = a0 + bv;
    out[(size_t)(row0 + 1) * 4096 + col] = a1 + bv;
}

extern "C" void kernel_launch(void* const* d_in, const int* in_sizes, int n_in,
                              void* d_out, int out_size, void* d_ws, size_t ws_size,
                              hipStream_t stream) {
    const float* x    = (const float*)d_in[0];
    const float* w    = (const float*)d_in[1];
    const float* bias = (const float*)d_in[2];
    float* out = (float*)d_out;

    const size_t nX = (size_t)M_DIM * K_DIM;
    const size_t nW = (size_t)N_DIM * K_DIM;
    const size_t need = (nX + nW) * sizeof(unsigned short);

    if (ws_size >= need) {
        unsigned short* xb = (unsigned short*)d_ws;
        unsigned short* wb = xb + nX;
        cvt_both_f32_to_bf16<<<3072, 256, 0, stream>>>(
            x, w, (unsigned short*)d_ws, (int)(nX / 4), (int)(nW / 4));
        hipError_t e = hipFuncSetAttribute(
            (const void*)gemm_bf16_256_8ph,
            hipFuncAttributeMaxDynamicSharedMemorySize, 131072);
        if (e == hipSuccess) {
            gemm_bf16_256_8ph<<<(M_DIM / 256) * (N_DIM / 256), 512, 131072, stream>>>(
                xb, wb, bias, out);
        } else {
            gemm_bf16_mfma<<<(M_DIM / 128) * (N_DIM / 128), 256, 0, stream>>>(
                xb, wb, bias, out);
        }
    } else {
        fallback_gemm_f32<<<dim3(N_DIM / 256, M_DIM / 2), 256, 0, stream>>>(x, w, bias, out);
    }
}